// Round 14
// baseline (161.169 us; speedup 1.0000x reference)
//
#include <hip/hip_runtime.h>
#include <cstddef>

#define CAP 64
#define BK_SHIFT 8      // 256 nodes per bucket
#define GSLOT 1024      // stage slots per (group,bucket): mean 512, 22-sigma headroom
#define CHUNK 2048      // edges per workgroup in k_part1 (256 thr x 8)

typedef unsigned int uint32;
typedef unsigned short ushort;
typedef __attribute__((ext_vector_type(8))) short short8;
typedef __attribute__((ext_vector_type(4))) float f32x4;
typedef __attribute__((ext_vector_type(4))) int int4v;
typedef __attribute__((ext_vector_type(4))) float float4v;

__device__ __forceinline__ float bf_lo(uint32 v) {
  union { uint32 u; float f; } c; c.u = v << 16; return c.f;
}
__device__ __forceinline__ float bf_hi(uint32 v) {
  union { uint32 u; float f; } c; c.u = v & 0xffff0000u; return c.f;
}
__device__ __forceinline__ uint32 pack_bf2(float a, float b) {  // RNE
  union { float f; uint32 u; } x, y; x.f = a; y.f = b;
  uint32 ua = x.u + 0x7fffu + ((x.u >> 16) & 1u);
  uint32 ub = y.u + 0x7fffu + ((y.u >> 16) & 1u);
  return (ua >> 16) | (ub & 0xffff0000u);
}
__device__ __forceinline__ ushort bf16_1(float x) {  // RNE scalar
  union { float f; uint32 u; } c; c.f = x;
  return (ushort)((c.u + 0x7fffu + ((c.u >> 16) & 1u)) >> 16);
}

union ABu { uint32 u[4]; short8 v; };

// Phase 1: partition edges into 256-node buckets (packed (r<<8)|(c&255)).
// Stage is XCD-grouped (g = blockIdx&7): each (g,bucket) slice appended by
// one XCD only -> tail line stays in that L2 -> full-line write combining.
__global__ __launch_bounds__(256) void k_part1(const int* __restrict__ ei,
                                               int* __restrict__ bcnt,
                                               int* __restrict__ stage,
                                               int E, int N, int NB) {
  __shared__ int hist[512];
  __shared__ int gbase[512];
  const int tid = threadIdx.x;
  const int g   = blockIdx.x & 7;
  const int base = blockIdx.x * CHUNK;
  for (int b = tid; b < NB; b += 256) hist[b] = 0;
  __syncthreads();
  int rr[8], cc[8], lp[8];
  #pragma unroll
  for (int j = 0; j < 8; j++) {
    int e = base + tid + j * 256;
    int r = -1, c = -1;
    if (e < E) {
      r = __builtin_nontemporal_load(&ei[e]);
      c = __builtin_nontemporal_load(&ei[(size_t)E + e]);
    }
    bool ok = ((unsigned)r < (unsigned)N) && ((unsigned)c < (unsigned)N);
    rr[j] = ok ? r : -1;
    cc[j] = c;
    lp[j] = ok ? atomicAdd(&hist[c >> BK_SHIFT], 1) : 0;
  }
  __syncthreads();
  for (int b = tid; b < NB; b += 256) {
    int h = hist[b];
    gbase[b] = h ? atomicAdd(&bcnt[g * NB + b], h) : 0;
  }
  __syncthreads();
  #pragma unroll
  for (int j = 0; j < 8; j++) {
    if (rr[j] >= 0) {
      int b = cc[j] >> BK_SHIFT;
      int pos = gbase[b] + lp[j];
      if (pos < GSLOT)
        stage[((size_t)(g * NB + b) << 10) + pos] = (rr[j] << 8) | (cc[j] & 255);
    }
  }
}

// Phase 2: one workgroup per bucket; reads its 8 group slices, csr writes in
// a 64KB window, self-padding to deg8, cnt coalesced. Block NB: folded k_wc
// + W1 -> Wt pre-convert ([col][k] bf16, 32KB, consumed by LDS-free gemm).
__global__ __launch_bounds__(256) void k_fill2(const int* __restrict__ stage,
                                               const int* __restrict__ bcnt,
                                               int* __restrict__ csr,
                                               int* __restrict__ cnt, int N, int NB,
                                               const float* __restrict__ W1,
                                               ushort* __restrict__ Wt,
                                               const float* __restrict__ W2,
                                               const float* __restrict__ Wfc,
                                               const float* __restrict__ b2,
                                               const float* __restrict__ bfc,
                                               float* __restrict__ wvo,
                                               float* __restrict__ c0) {
  const int b = blockIdx.x;
  const int tid = threadIdx.x;
  if (b == NB) {                      // folded k_wc + W1 pre-convert
    if (tid < 128) {
      float s = 0.f;
      #pragma unroll 8
      for (int j = 0; j < 64; j++) s += W2[tid * 64 + j] * Wfc[j];
      wvo[tid] = s;
      if (tid == 0) {
        float cc = 0.f;
        for (int j = 0; j < 64; j++) cc += b2[j] * Wfc[j];
        c0[0] = cc + bfc[0];
      }
    }
    for (int idx = tid; idx < 16384; idx += 256) {
      int c = idx >> 7, k = idx & 127;
      Wt[c * 128 + k] = bf16_1(W1[k * 128 + c]);   // transpose + bf16
    }
    return;
  }
  __shared__ int lc[256];
  lc[tid] = 0;
  __syncthreads();
  const int node0 = b << BK_SHIFT;
  for (int g = 0; g < 8; g++) {
    int m = bcnt[g * NB + b]; if (m > GSLOT) m = GSLOT;
    const int* __restrict__ sb = stage + ((size_t)(g * NB + b) << 10);
    for (int e = tid; e < m; e += 256) {
      int v = __builtin_nontemporal_load(&sb[e]);
      int cl = v & 255;
      int pos = atomicAdd(&lc[cl], 1);
      if (pos < CAP) csr[(size_t)(node0 + cl) * CAP + pos] = v >> 8;
    }
  }
  __syncthreads();
  int node = node0 + tid;
  if (node < N) {
    int d = lc[tid]; if (d > CAP) d = CAP;
    cnt[node] = lc[tid];                 // true degree (rsqrt uses cnt+1)
    int d8 = (d + 7) & ~7; if (d8 > CAP) d8 = CAP;
    for (int p = d; p < d8; p++) csr[(size_t)node * CAP + p] = node;  // self-pad
  }
}

// Xh = bf16( dinv[row] * (X @ W1)[row,:] ) via bf16 MFMA 16x16x32.
// LDS-free: B-fragments loaded straight from pre-converted Wt (32KB, L2-hot).
// Fragment contents identical to R7's verified swizzled-LDS path.
__global__ __launch_bounds__(256) void k_gemm(const float* __restrict__ X,
                                              const ushort* __restrict__ Wt,
                                              const int* __restrict__ cnt,
                                              ushort* __restrict__ Xh, int M) {
  const int tid  = threadIdx.x;
  const int lane = tid & 63;
  const int wv   = tid >> 6;      // wave 0..3
  const int cl   = lane & 15;
  const int g    = lane >> 4;
  const int rb = blockIdx.x * 64 + wv * 16;

  int rowc = rb + cl; if (rowc >= M) rowc = M - 1;
  const float* xr = X + (size_t)rowc * 128;
  ABu af[4];
  #pragma unroll
  for (int kk = 0; kk < 4; kk++) {
    float4v p = __builtin_nontemporal_load((const float4v*)&xr[kk * 32 + g * 8]);
    float4v q = __builtin_nontemporal_load((const float4v*)&xr[kk * 32 + g * 8 + 4]);
    af[kk].u[0] = pack_bf2(p.x, p.y);
    af[kk].u[1] = pack_bf2(p.z, p.w);
    af[kk].u[2] = pack_bf2(q.x, q.y);
    af[kk].u[3] = pack_bf2(q.z, q.w);
  }

  float dvr[4];
  #pragma unroll
  for (int r = 0; r < 4; r++) {
    int rw = rb + g * 4 + r; if (rw >= M) rw = M - 1;
    dvr[r] = rsqrtf((float)(cnt[rw] + 1));
  }

  #pragma unroll
  for (int ct = 0; ct < 8; ct++) {
    const ushort* wrow = Wt + (ct * 16 + cl) * 128;   // col = ct*16+cl, k-major
    f32x4 acc = {0.f, 0.f, 0.f, 0.f};
    #pragma unroll
    for (int kk = 0; kk < 4; kk++) {
      short8 bfrag = *(const short8*)(wrow + kk * 32 + g * 8);
      acc = __builtin_amdgcn_mfma_f32_16x16x32_bf16(af[kk].v, bfrag, acc, 0, 0, 0);
    }
    #pragma unroll
    for (int r = 0; r < 4; r++) {
      int rw = rb + g * 4 + r;
      if (rw < M) Xh[(size_t)rw * 128 + ct * 16 + cl] = bf16_1(dvr[r] * acc[r]);
    }
  }
}

// One wave per node; tail-free unroll-8 gather over pre-scaled bf16 rows.
__global__ __launch_bounds__(256) void k_agg1(const uint32* __restrict__ Xh,
                                              const int* __restrict__ csr,
                                              const int* __restrict__ cnt,
                                              const float* __restrict__ b1,
                                              const float* __restrict__ wv,
                                              float* __restrict__ dz, int N) {
  int wid = (blockIdx.x * 256 + threadIdx.x) >> 6;
  int lane = threadIdx.x & 63;
  if (wid >= N) return;
  const int i = wid;
  int cv = cnt[i];
  int deg = cv; if (deg > CAP) deg = CAP;
  const int deg8 = (deg + 7) & ~7;
  const float di = rsqrtf((float)(cv + 1));
  int edge_reg = i;
  if (lane < deg8) edge_reg = __builtin_nontemporal_load(&csr[(size_t)i * CAP + lane]);

  uint32 vs = Xh[(size_t)i * 64 + lane];          // self-loop row
  float a0x = 0.f, a0y = 0.f, a1x = 0.f, a1y = 0.f;
  float a2x = 0.f, a2y = 0.f, a3x = 0.f, a3y = 0.f;
  float a4x = 0.f, a4y = 0.f, a5x = 0.f, a5y = 0.f;
  float a6x = 0.f, a6y = 0.f, a7x = 0.f, a7y = 0.f;

  for (int e = 0; e < deg8; e += 8) {
    int s0 = __builtin_amdgcn_readlane(edge_reg, e + 0);
    int s1 = __builtin_amdgcn_readlane(edge_reg, e + 1);
    int s2 = __builtin_amdgcn_readlane(edge_reg, e + 2);
    int s3 = __builtin_amdgcn_readlane(edge_reg, e + 3);
    int s4 = __builtin_amdgcn_readlane(edge_reg, e + 4);
    int s5 = __builtin_amdgcn_readlane(edge_reg, e + 5);
    int s6 = __builtin_amdgcn_readlane(edge_reg, e + 6);
    int s7 = __builtin_amdgcn_readlane(edge_reg, e + 7);
    uint32 v0 = Xh[(size_t)s0 * 64 + lane];
    uint32 v1 = Xh[(size_t)s1 * 64 + lane];
    uint32 v2 = Xh[(size_t)s2 * 64 + lane];
    uint32 v3 = Xh[(size_t)s3 * 64 + lane];
    uint32 v4 = Xh[(size_t)s4 * 64 + lane];
    uint32 v5 = Xh[(size_t)s5 * 64 + lane];
    uint32 v6 = Xh[(size_t)s6 * 64 + lane];
    uint32 v7 = Xh[(size_t)s7 * 64 + lane];
    a0x += bf_lo(v0); a0y += bf_hi(v0);
    a1x += bf_lo(v1); a1y += bf_hi(v1);
    a2x += bf_lo(v2); a2y += bf_hi(v2);
    a3x += bf_lo(v3); a3y += bf_hi(v3);
    a4x += bf_lo(v4); a4y += bf_hi(v4);
    a5x += bf_lo(v5); a5y += bf_hi(v5);
    a6x += bf_lo(v6); a6y += bf_hi(v6);
    a7x += bf_lo(v7); a7y += bf_hi(v7);
  }
  const float selfc = 1.0f - (float)(deg8 - deg);
  float sx = ((a0x + a1x) + (a2x + a3x)) + ((a4x + a5x) + (a6x + a7x));
  float sy = ((a0y + a1y) + (a2y + a3y)) + ((a4y + a5y) + (a6y + a7y));
  sx = fmaf(selfc, bf_lo(vs), sx);
  sy = fmaf(selfc, bf_hi(vs), sy);

  float2 bb = *(const float2*)&b1[lane * 2];
  float h0 = fmaxf(fmaf(di, sx, bb.x), 0.f);
  float h1 = fmaxf(fmaf(di, sy, bb.y), 0.f);
  float2 ww = *(const float2*)&wv[lane * 2];
  float part = fmaf(h0, ww.x, h1 * ww.y);
  #pragma unroll
  for (int m = 32; m > 0; m >>= 1) part += __shfl_xor(part, m, 64);
  if (lane == 0) dz[i] = di * part;
}

// out[i] = c0 + dinv[i] * (dz[i] + sum_in dz[src]); int4 csr loads over the
// self-padded deg8 range, padding corrected via (1 - npad) * dz[i].
__global__ __launch_bounds__(256) void k_out(const float* __restrict__ dz,
                                             const int* __restrict__ csr,
                                             const int* __restrict__ cnt,
                                             const float* __restrict__ c0,
                                             float* __restrict__ out, int N) {
  int i = blockIdx.x * 256 + threadIdx.x;
  if (i >= N) return;
  int cv = cnt[i];
  int deg = cv; if (deg > CAP) deg = CAP;
  const int deg8 = (deg + 7) & ~7;
  const int4v* __restrict__ edges = (const int4v*)(csr + (size_t)i * CAP);
  float s0 = (1.0f - (float)(deg8 - deg)) * dz[i];
  float s1 = 0.f, s2 = 0.f, s3 = 0.f;
  for (int e4 = 0; e4 < (deg8 >> 2); e4 += 2) {
    int4v q0 = __builtin_nontemporal_load(&edges[e4]);
    int4v q1 = __builtin_nontemporal_load(&edges[e4 + 1]);
    s0 += dz[q0.x]; s1 += dz[q0.y]; s2 += dz[q0.z]; s3 += dz[q0.w];
    s0 += dz[q1.x]; s1 += dz[q1.y]; s2 += dz[q1.z]; s3 += dz[q1.w];
  }
  out[i] = rsqrtf((float)(cv + 1)) * ((s0 + s1) + (s2 + s3)) + c0[0];
}

extern "C" void kernel_launch(void* const* d_in, const int* in_sizes, int n_in,
                              void* d_out, int out_size, void* d_ws, size_t ws_size,
                              hipStream_t stream) {
  const float* x   = (const float*)d_in[0];
  const int*   ei  = (const int*)d_in[1];   // int inputs arrive as int32
  // d_in[2] edge_weight: unused by reference
  const float* W1  = (const float*)d_in[3];
  const float* b1  = (const float*)d_in[4];
  const float* W2  = (const float*)d_in[5];
  const float* b2  = (const float*)d_in[6];
  const float* Wfc = (const float*)d_in[7];
  const float* bfc = (const float*)d_in[8];
  float* out = (float*)d_out;

  const int N = in_sizes[0] / 128;   // 100000
  const int E = in_sizes[1] / 2;     // 1600000
  const int NB = (N + 255) >> 8;     // 391 buckets

  // workspace layout (~65 MB)
  char* ws = (char*)d_ws;
  ushort* Xh = (ushort*)(ws);                               // N*128 bf16, 25.6MB
  size_t off = (size_t)N * 256;
  int* csr   = (int*)(ws + off); off += (size_t)N * 256;    // 25.6MB
  int* stage = (int*)(ws + off); off += (size_t)8 * NB * GSLOT * 4;  // 12.81MB
  int* cnt   = (int*)(ws + off); off += (size_t)N * 4;
  float* dz  = (float*)(ws + off); off += (size_t)N * 4;
  int* bcnt  = (int*)(ws + off); off += (size_t)8 * NB * 4;
  ushort* Wt = (ushort*)(ws + off); off += 16384 * 2;       // 32KB bf16 W1^T
  float* wv  = (float*)(ws + off); off += 512;
  float* c0  = (float*)(ws + off);

  hipMemsetAsync(bcnt, 0, (size_t)8 * NB * 4, stream);
  hipLaunchKernelGGL(k_part1, dim3((E + CHUNK - 1) / CHUNK), dim3(256), 0, stream,
                     ei, bcnt, stage, E, N, NB);
  hipLaunchKernelGGL(k_fill2, dim3(NB + 1), dim3(256), 0, stream,
                     stage, bcnt, csr, cnt, N, NB, W1, Wt, W2, Wfc, b2, bfc, wv, c0);
  hipLaunchKernelGGL(k_gemm,  dim3((N + 63) / 64), dim3(256), 0, stream,
                     x, Wt, cnt, Xh, N);
  hipLaunchKernelGGL(k_agg1, dim3(((size_t)N * 64 + 255) / 256), dim3(256), 0, stream,
                     (const uint32*)Xh, csr, cnt, b1, wv, dz, N);
  hipLaunchKernelGGL(k_out,  dim3((N + 255) / 256), dim3(256), 0, stream,
                     dz, csr, cnt, c0, out, N);
}

// Round 15
// 143.863 us; speedup vs baseline: 1.1203x; 1.1203x over previous
//
#include <hip/hip_runtime.h>
#include <cstddef>

#define CAP 64
#define BK_SHIFT 8      // 256 nodes per bucket
#define GSLOT 1024      // stage slots per (group,bucket): mean 512, 22-sigma headroom
#define CHUNK 2048      // edges per workgroup in k_part1 (256 thr x 8)

typedef unsigned int uint32;
typedef unsigned short ushort;
typedef __attribute__((ext_vector_type(8))) short short8;
typedef __attribute__((ext_vector_type(4))) float f32x4;
typedef __attribute__((ext_vector_type(4))) int int4v;
typedef __attribute__((ext_vector_type(4))) float float4v;

__device__ __forceinline__ float bf_lo(uint32 v) {
  union { uint32 u; float f; } c; c.u = v << 16; return c.f;
}
__device__ __forceinline__ float bf_hi(uint32 v) {
  union { uint32 u; float f; } c; c.u = v & 0xffff0000u; return c.f;
}
__device__ __forceinline__ uint32 pack_bf2(float a, float b) {  // RNE
  union { float f; uint32 u; } x, y; x.f = a; y.f = b;
  uint32 ua = x.u + 0x7fffu + ((x.u >> 16) & 1u);
  uint32 ub = y.u + 0x7fffu + ((y.u >> 16) & 1u);
  return (ua >> 16) | (ub & 0xffff0000u);
}
__device__ __forceinline__ ushort bf16_1(float x) {  // RNE scalar
  union { float f; uint32 u; } c; c.f = x;
  return (ushort)((c.u + 0x7fffu + ((c.u >> 16) & 1u)) >> 16);
}

union ABu { uint32 u[4]; short8 v; };

// Phase 1: partition edges into 256-node buckets (packed (r<<8)|(c&255)).
// Stage is XCD-grouped (g = blockIdx&7): each (g,bucket) slice appended by
// one XCD only -> tail line stays in that L2 -> full-line write combining.
__global__ __launch_bounds__(256) void k_part1(const int* __restrict__ ei,
                                               int* __restrict__ bcnt,
                                               int* __restrict__ stage,
                                               int E, int N, int NB) {
  __shared__ int hist[512];
  __shared__ int gbase[512];
  const int tid = threadIdx.x;
  const int g   = blockIdx.x & 7;
  const int base = blockIdx.x * CHUNK;
  for (int b = tid; b < NB; b += 256) hist[b] = 0;
  __syncthreads();
  int rr[8], cc[8], lp[8];
  #pragma unroll
  for (int j = 0; j < 8; j++) {
    int e = base + tid + j * 256;
    int r = -1, c = -1;
    if (e < E) {
      r = __builtin_nontemporal_load(&ei[e]);
      c = __builtin_nontemporal_load(&ei[(size_t)E + e]);
    }
    bool ok = ((unsigned)r < (unsigned)N) && ((unsigned)c < (unsigned)N);
    rr[j] = ok ? r : -1;
    cc[j] = c;
    lp[j] = ok ? atomicAdd(&hist[c >> BK_SHIFT], 1) : 0;
  }
  __syncthreads();
  for (int b = tid; b < NB; b += 256) {
    int h = hist[b];
    gbase[b] = h ? atomicAdd(&bcnt[g * NB + b], h) : 0;
  }
  __syncthreads();
  #pragma unroll
  for (int j = 0; j < 8; j++) {
    if (rr[j] >= 0) {
      int b = cc[j] >> BK_SHIFT;
      int pos = gbase[b] + lp[j];
      if (pos < GSLOT)
        stage[((size_t)(g * NB + b) << 10) + pos] = (rr[j] << 8) | (cc[j] & 255);
    }
  }
}

// Phase 2: one workgroup per bucket; reads its 8 group slices, csr writes in
// a 64KB window, self-padding to deg8, cnt coalesced. Block NB: folded k_wc
// + W1 -> Wt pre-convert ([col][k] bf16, 32KB, staged wide by k_gemm).
__global__ __launch_bounds__(256) void k_fill2(const int* __restrict__ stage,
                                               const int* __restrict__ bcnt,
                                               int* __restrict__ csr,
                                               int* __restrict__ cnt, int N, int NB,
                                               const float* __restrict__ W1,
                                               ushort* __restrict__ Wt,
                                               const float* __restrict__ W2,
                                               const float* __restrict__ Wfc,
                                               const float* __restrict__ b2,
                                               const float* __restrict__ bfc,
                                               float* __restrict__ wvo,
                                               float* __restrict__ c0) {
  const int b = blockIdx.x;
  const int tid = threadIdx.x;
  if (b == NB) {                      // folded k_wc + W1 pre-convert
    if (tid < 128) {
      float s = 0.f;
      #pragma unroll 8
      for (int j = 0; j < 64; j++) s += W2[tid * 64 + j] * Wfc[j];
      wvo[tid] = s;
      if (tid == 0) {
        float cc = 0.f;
        for (int j = 0; j < 64; j++) cc += b2[j] * Wfc[j];
        c0[0] = cc + bfc[0];
      }
    }
    for (int idx = tid; idx < 16384; idx += 256) {
      int c = idx >> 7, k = idx & 127;
      Wt[c * 128 + k] = bf16_1(W1[k * 128 + c]);   // transpose + bf16
    }
    return;
  }
  __shared__ int lc[256];
  lc[tid] = 0;
  __syncthreads();
  const int node0 = b << BK_SHIFT;
  for (int g = 0; g < 8; g++) {
    int m = bcnt[g * NB + b]; if (m > GSLOT) m = GSLOT;
    const int* __restrict__ sb = stage + ((size_t)(g * NB + b) << 10);
    for (int e = tid; e < m; e += 256) {
      int v = __builtin_nontemporal_load(&sb[e]);
      int cl = v & 255;
      int pos = atomicAdd(&lc[cl], 1);
      if (pos < CAP) csr[(size_t)(node0 + cl) * CAP + pos] = v >> 8;
    }
  }
  __syncthreads();
  int node = node0 + tid;
  if (node < N) {
    int d = lc[tid]; if (d > CAP) d = CAP;
    cnt[node] = lc[tid];                 // true degree (rsqrt uses cnt+1)
    int d8 = (d + 7) & ~7; if (d8 > CAP) d8 = CAP;
    for (int p = d; p < d8; p++) csr[(size_t)node * CAP + p] = node;  // self-pad
  }
}

// Xh = bf16( dinv[row] * (X @ W1)[row,:] ) via bf16 MFMA 16x16x32.
// 512 threads = 8 waves = 128 rows/block. W staged to swizzled LDS from the
// pre-converted Wt in 4 WIDE iterations/thread (16B load -> 16B ds_write;
// one swizzle granule per chunk). Fragment math identical to R7-verified.
__global__ __launch_bounds__(512) void k_gemm(const float* __restrict__ X,
                                              const ushort* __restrict__ Wt,
                                              const int* __restrict__ cnt,
                                              ushort* __restrict__ Xh, int M) {
  __shared__ ushort WtT[16384];   // 128 cols x 128 k, swizzled, 32 KB
  const int tid  = threadIdx.x;
  const int lane = tid & 63;
  const int wv   = tid >> 6;      // wave 0..7
  const int cl   = lane & 15;
  const int g    = lane >> 4;
  const int rb = blockIdx.x * 128 + wv * 16;

  // A fragments: per lane row rb+cl, k = 32kk + 8g + j  (j=0..7)
  int rowc = rb + cl; if (rowc >= M) rowc = M - 1;
  const float* xr = X + (size_t)rowc * 128;
  ABu af[4];
  #pragma unroll
  for (int kk = 0; kk < 4; kk++) {
    float4v p = __builtin_nontemporal_load((const float4v*)&xr[kk * 32 + g * 8]);
    float4v q = __builtin_nontemporal_load((const float4v*)&xr[kk * 32 + g * 8 + 4]);
    af[kk].u[0] = pack_bf2(p.x, p.y);
    af[kk].u[1] = pack_bf2(p.z, p.w);
    af[kk].u[2] = pack_bf2(q.x, q.y);
    af[kk].u[3] = pack_bf2(q.z, q.w);
  }

  float dvr[4];
  #pragma unroll
  for (int r = 0; r < 4; r++) {
    int rw = rb + g * 4 + r; if (rw >= M) rw = M - 1;
    dvr[r] = rsqrtf((float)(cnt[rw] + 1));
  }

  // wide staging: chunk id -> (c = id>>4, j = id&15); 16B from Wt row c,
  // k in [8j, 8j+8) -> one granule at c*256 + ((j ^ ((c&15)>>1))&15)*16
  #pragma unroll
  for (int it = 0; it < 4; it++) {
    int id = tid + it * 512;
    int c = id >> 4, j = id & 15;
    int4v chunk = *(const int4v*)((const char*)Wt + id * 16);
    int gr = (j ^ ((c & 15) >> 1)) & 15;
    *(int4v*)((char*)WtT + c * 256 + gr * 16) = chunk;
  }
  __syncthreads();

  #pragma unroll
  for (int ct = 0; ct < 8; ct++) {
    const char* wrow = (const char*)WtT + (ct * 16 + cl) * 256;
    f32x4 acc = {0.f, 0.f, 0.f, 0.f};
    #pragma unroll
    for (int kk = 0; kk < 4; kk++) {
      int grn = ((4 * kk + g) ^ (cl >> 1)) & 15;
      short8 bfrag = *(const short8*)(wrow + (grn << 4));
      acc = __builtin_amdgcn_mfma_f32_16x16x32_bf16(af[kk].v, bfrag, acc, 0, 0, 0);
    }
    #pragma unroll
    for (int r = 0; r < 4; r++) {
      int rw = rb + g * 4 + r;
      if (rw < M) Xh[(size_t)rw * 128 + ct * 16 + cl] = bf16_1(dvr[r] * acc[r]);
    }
  }
}

// One wave per node; tail-free unroll-8 gather over pre-scaled bf16 rows.
__global__ __launch_bounds__(256) void k_agg1(const uint32* __restrict__ Xh,
                                              const int* __restrict__ csr,
                                              const int* __restrict__ cnt,
                                              const float* __restrict__ b1,
                                              const float* __restrict__ wv,
                                              float* __restrict__ dz, int N) {
  int wid = (blockIdx.x * 256 + threadIdx.x) >> 6;
  int lane = threadIdx.x & 63;
  if (wid >= N) return;
  const int i = wid;
  int cv = cnt[i];
  int deg = cv; if (deg > CAP) deg = CAP;
  const int deg8 = (deg + 7) & ~7;
  const float di = rsqrtf((float)(cv + 1));
  int edge_reg = i;
  if (lane < deg8) edge_reg = __builtin_nontemporal_load(&csr[(size_t)i * CAP + lane]);

  uint32 vs = Xh[(size_t)i * 64 + lane];          // self-loop row
  float a0x = 0.f, a0y = 0.f, a1x = 0.f, a1y = 0.f;
  float a2x = 0.f, a2y = 0.f, a3x = 0.f, a3y = 0.f;
  float a4x = 0.f, a4y = 0.f, a5x = 0.f, a5y = 0.f;
  float a6x = 0.f, a6y = 0.f, a7x = 0.f, a7y = 0.f;

  for (int e = 0; e < deg8; e += 8) {
    int s0 = __builtin_amdgcn_readlane(edge_reg, e + 0);
    int s1 = __builtin_amdgcn_readlane(edge_reg, e + 1);
    int s2 = __builtin_amdgcn_readlane(edge_reg, e + 2);
    int s3 = __builtin_amdgcn_readlane(edge_reg, e + 3);
    int s4 = __builtin_amdgcn_readlane(edge_reg, e + 4);
    int s5 = __builtin_amdgcn_readlane(edge_reg, e + 5);
    int s6 = __builtin_amdgcn_readlane(edge_reg, e + 6);
    int s7 = __builtin_amdgcn_readlane(edge_reg, e + 7);
    uint32 v0 = Xh[(size_t)s0 * 64 + lane];
    uint32 v1 = Xh[(size_t)s1 * 64 + lane];
    uint32 v2 = Xh[(size_t)s2 * 64 + lane];
    uint32 v3 = Xh[(size_t)s3 * 64 + lane];
    uint32 v4 = Xh[(size_t)s4 * 64 + lane];
    uint32 v5 = Xh[(size_t)s5 * 64 + lane];
    uint32 v6 = Xh[(size_t)s6 * 64 + lane];
    uint32 v7 = Xh[(size_t)s7 * 64 + lane];
    a0x += bf_lo(v0); a0y += bf_hi(v0);
    a1x += bf_lo(v1); a1y += bf_hi(v1);
    a2x += bf_lo(v2); a2y += bf_hi(v2);
    a3x += bf_lo(v3); a3y += bf_hi(v3);
    a4x += bf_lo(v4); a4y += bf_hi(v4);
    a5x += bf_lo(v5); a5y += bf_hi(v5);
    a6x += bf_lo(v6); a6y += bf_hi(v6);
    a7x += bf_lo(v7); a7y += bf_hi(v7);
  }
  const float selfc = 1.0f - (float)(deg8 - deg);
  float sx = ((a0x + a1x) + (a2x + a3x)) + ((a4x + a5x) + (a6x + a7x));
  float sy = ((a0y + a1y) + (a2y + a3y)) + ((a4y + a5y) + (a6y + a7y));
  sx = fmaf(selfc, bf_lo(vs), sx);
  sy = fmaf(selfc, bf_hi(vs), sy);

  float2 bb = *(const float2*)&b1[lane * 2];
  float h0 = fmaxf(fmaf(di, sx, bb.x), 0.f);
  float h1 = fmaxf(fmaf(di, sy, bb.y), 0.f);
  float2 ww = *(const float2*)&wv[lane * 2];
  float part = fmaf(h0, ww.x, h1 * ww.y);
  #pragma unroll
  for (int m = 32; m > 0; m >>= 1) part += __shfl_xor(part, m, 64);
  if (lane == 0) dz[i] = di * part;
}

// out[i] = c0 + dinv[i] * (dz[i] + sum_in dz[src]); int4 csr loads over the
// self-padded deg8 range, padding corrected via (1 - npad) * dz[i].
__global__ __launch_bounds__(256) void k_out(const float* __restrict__ dz,
                                             const int* __restrict__ csr,
                                             const int* __restrict__ cnt,
                                             const float* __restrict__ c0,
                                             float* __restrict__ out, int N) {
  int i = blockIdx.x * 256 + threadIdx.x;
  if (i >= N) return;
  int cv = cnt[i];
  int deg = cv; if (deg > CAP) deg = CAP;
  const int deg8 = (deg + 7) & ~7;
  const int4v* __restrict__ edges = (const int4v*)(csr + (size_t)i * CAP);
  float s0 = (1.0f - (float)(deg8 - deg)) * dz[i];
  float s1 = 0.f, s2 = 0.f, s3 = 0.f;
  for (int e4 = 0; e4 < (deg8 >> 2); e4 += 2) {
    int4v q0 = __builtin_nontemporal_load(&edges[e4]);
    int4v q1 = __builtin_nontemporal_load(&edges[e4 + 1]);
    s0 += dz[q0.x]; s1 += dz[q0.y]; s2 += dz[q0.z]; s3 += dz[q0.w];
    s0 += dz[q1.x]; s1 += dz[q1.y]; s2 += dz[q1.z]; s3 += dz[q1.w];
  }
  out[i] = rsqrtf((float)(cv + 1)) * ((s0 + s1) + (s2 + s3)) + c0[0];
}

extern "C" void kernel_launch(void* const* d_in, const int* in_sizes, int n_in,
                              void* d_out, int out_size, void* d_ws, size_t ws_size,
                              hipStream_t stream) {
  const float* x   = (const float*)d_in[0];
  const int*   ei  = (const int*)d_in[1];   // int inputs arrive as int32
  // d_in[2] edge_weight: unused by reference
  const float* W1  = (const float*)d_in[3];
  const float* b1  = (const float*)d_in[4];
  const float* W2  = (const float*)d_in[5];
  const float* b2  = (const float*)d_in[6];
  const float* Wfc = (const float*)d_in[7];
  const float* bfc = (const float*)d_in[8];
  float* out = (float*)d_out;

  const int N = in_sizes[0] / 128;   // 100000
  const int E = in_sizes[1] / 2;     // 1600000
  const int NB = (N + 255) >> 8;     // 391 buckets

  // workspace layout (~65 MB)
  char* ws = (char*)d_ws;
  ushort* Xh = (ushort*)(ws);                               // N*128 bf16, 25.6MB
  size_t off = (size_t)N * 256;
  int* csr   = (int*)(ws + off); off += (size_t)N * 256;    // 25.6MB
  int* stage = (int*)(ws + off); off += (size_t)8 * NB * GSLOT * 4;  // 12.81MB
  int* cnt   = (int*)(ws + off); off += (size_t)N * 4;
  float* dz  = (float*)(ws + off); off += (size_t)N * 4;
  int* bcnt  = (int*)(ws + off); off += (size_t)8 * NB * 4;
  ushort* Wt = (ushort*)(ws + off); off += 16384 * 2;       // 32KB bf16 W1^T
  float* wv  = (float*)(ws + off); off += 512;
  float* c0  = (float*)(ws + off);

  hipMemsetAsync(bcnt, 0, (size_t)8 * NB * 4, stream);
  hipLaunchKernelGGL(k_part1, dim3((E + CHUNK - 1) / CHUNK), dim3(256), 0, stream,
                     ei, bcnt, stage, E, N, NB);
  hipLaunchKernelGGL(k_fill2, dim3(NB + 1), dim3(256), 0, stream,
                     stage, bcnt, csr, cnt, N, NB, W1, Wt, W2, Wfc, b2, bfc, wv, c0);
  hipLaunchKernelGGL(k_gemm,  dim3((N + 127) / 128), dim3(512), 0, stream,
                     x, Wt, cnt, Xh, N);
  hipLaunchKernelGGL(k_agg1, dim3(((size_t)N * 64 + 255) / 256), dim3(256), 0, stream,
                     (const uint32*)Xh, csr, cnt, b1, wv, dz, N);
  hipLaunchKernelGGL(k_out,  dim3((N + 255) / 256), dim3(256), 0, stream,
                     dz, csr, cnt, c0, out, N);
}

// Round 16
// 141.960 us; speedup vs baseline: 1.1353x; 1.0134x over previous
//
#include <hip/hip_runtime.h>
#include <cstddef>

#define CAP 64
#define BK_SHIFT 8      // 256 nodes per bucket
#define GSLOT 1024      // stage slots per (group,bucket): mean 512, 22-sigma headroom
#define CHUNK 2048      // edges per workgroup in k_part1 (512 thr x 4)

typedef unsigned int uint32;
typedef unsigned short ushort;
typedef __attribute__((ext_vector_type(8))) short short8;
typedef __attribute__((ext_vector_type(4))) float f32x4;
typedef __attribute__((ext_vector_type(4))) int int4v;
typedef __attribute__((ext_vector_type(4))) float float4v;

__device__ __forceinline__ float bf_lo(uint32 v) {
  union { uint32 u; float f; } c; c.u = v << 16; return c.f;
}
__device__ __forceinline__ float bf_hi(uint32 v) {
  union { uint32 u; float f; } c; c.u = v & 0xffff0000u; return c.f;
}
__device__ __forceinline__ uint32 pack_bf2(float a, float b) {  // RNE
  union { float f; uint32 u; } x, y; x.f = a; y.f = b;
  uint32 ua = x.u + 0x7fffu + ((x.u >> 16) & 1u);
  uint32 ub = y.u + 0x7fffu + ((y.u >> 16) & 1u);
  return (ua >> 16) | (ub & 0xffff0000u);
}
__device__ __forceinline__ ushort bf16_1(float x) {  // RNE scalar
  union { float f; uint32 u; } c; c.f = x;
  return (ushort)((c.u + 0x7fffu + ((c.u >> 16) & 1u)) >> 16);
}

union ABu { uint32 u[4]; short8 v; };

// Phase 1: partition edges into 256-node buckets (packed (r<<8)|(c&255)).
// 512 threads, int4 loads (4 edges/thread). Stage is XCD-grouped
// (g = blockIdx&7): each (g,bucket) slice appended by one XCD only ->
// tail line stays in that L2 -> full-line write combining.
__global__ __launch_bounds__(512) void k_part1(const int* __restrict__ ei,
                                               int* __restrict__ bcnt,
                                               int* __restrict__ stage,
                                               int E, int N, int NB) {
  __shared__ int hist[512];
  __shared__ int gbase[512];
  const int tid = threadIdx.x;
  const int g   = blockIdx.x & 7;
  const int e0  = blockIdx.x * CHUNK + tid * 4;
  hist[tid] = 0;
  __syncthreads();
  int4v r4 = {-1, -1, -1, -1}, c4 = {-1, -1, -1, -1};
  if (e0 + 3 < E && ((E & 3) == 0)) {
    r4 = __builtin_nontemporal_load((const int4v*)&ei[e0]);
    c4 = __builtin_nontemporal_load((const int4v*)&ei[(size_t)E + e0]);
  } else {
    #pragma unroll
    for (int j = 0; j < 4; j++)
      if (e0 + j < E) {
        ((int*)&r4)[j] = ei[e0 + j];
        ((int*)&c4)[j] = ei[(size_t)E + e0 + j];
      }
  }
  int rr[4], cc[4], lp[4];
  #pragma unroll
  for (int j = 0; j < 4; j++) {
    int r = ((int*)&r4)[j], c = ((int*)&c4)[j];
    bool ok = ((unsigned)r < (unsigned)N) && ((unsigned)c < (unsigned)N);
    rr[j] = ok ? r : -1;
    cc[j] = c;
    lp[j] = ok ? atomicAdd(&hist[c >> BK_SHIFT], 1) : 0;
  }
  __syncthreads();
  if (tid < NB) {
    int h = hist[tid];
    gbase[tid] = h ? atomicAdd(&bcnt[g * NB + tid], h) : 0;
  }
  __syncthreads();
  #pragma unroll
  for (int j = 0; j < 4; j++) {
    if (rr[j] >= 0) {
      int b = cc[j] >> BK_SHIFT;
      int pos = gbase[b] + lp[j];
      if (pos < GSLOT)
        stage[((size_t)(g * NB + b) << 10) + pos] = (rr[j] << 8) | (cc[j] & 255);
    }
  }
}

// Phase 2: one workgroup per bucket, 512 threads = 8 x 64-thread groups each
// consuming one group-slice CONCURRENTLY (csr order within a row is
// irrelevant). csr writes in a 64KB window, self-padding to deg8, cnt
// coalesced. Block NB: folded k_wc + W1 -> Wt pre-convert.
__global__ __launch_bounds__(512) void k_fill2(const int* __restrict__ stage,
                                               const int* __restrict__ bcnt,
                                               int* __restrict__ csr,
                                               int* __restrict__ cnt, int N, int NB,
                                               const float* __restrict__ W1,
                                               ushort* __restrict__ Wt,
                                               const float* __restrict__ W2,
                                               const float* __restrict__ Wfc,
                                               const float* __restrict__ b2,
                                               const float* __restrict__ bfc,
                                               float* __restrict__ wvo,
                                               float* __restrict__ c0) {
  const int b = blockIdx.x;
  const int tid = threadIdx.x;
  if (b == NB) {                      // folded k_wc + W1 pre-convert
    if (tid < 128) {
      float s = 0.f;
      #pragma unroll 8
      for (int j = 0; j < 64; j++) s += W2[tid * 64 + j] * Wfc[j];
      wvo[tid] = s;
      if (tid == 0) {
        float cc = 0.f;
        for (int j = 0; j < 64; j++) cc += b2[j] * Wfc[j];
        c0[0] = cc + bfc[0];
      }
    }
    for (int idx = tid; idx < 16384; idx += 512) {
      int c = idx >> 7, k = idx & 127;
      Wt[c * 128 + k] = bf16_1(W1[k * 128 + c]);   // transpose + bf16
    }
    return;
  }
  __shared__ int lc[256];
  if (tid < 256) lc[tid] = 0;
  __syncthreads();
  const int node0 = b << BK_SHIFT;
  const int gq = tid >> 6;            // group slice 0..7
  const int lt = tid & 63;
  int m = bcnt[gq * NB + b]; if (m > GSLOT) m = GSLOT;
  const int* __restrict__ sb = stage + ((size_t)(gq * NB + b) << 10);
  for (int e = lt; e < m; e += 64) {
    int v = __builtin_nontemporal_load(&sb[e]);
    int cl = v & 255;
    int pos = atomicAdd(&lc[cl], 1);
    if (pos < CAP) csr[(size_t)(node0 + cl) * CAP + pos] = v >> 8;
  }
  __syncthreads();
  int node = node0 + tid;
  if (tid < 256 && node < N) {
    int d = lc[tid]; if (d > CAP) d = CAP;
    cnt[node] = lc[tid];                 // true degree (rsqrt uses cnt+1)
    int d8 = (d + 7) & ~7; if (d8 > CAP) d8 = CAP;
    for (int p = d; p < d8; p++) csr[(size_t)node * CAP + p] = node;  // self-pad
  }
}

// Xh = bf16( dinv[row] * (X @ W1)[row,:] ) via bf16 MFMA 16x16x32.
// 512 threads = 8 waves = 128 rows/block. W staged to swizzled LDS from the
// pre-converted Wt in 4 WIDE iterations/thread (16B load -> 16B ds_write).
__global__ __launch_bounds__(512) void k_gemm(const float* __restrict__ X,
                                              const ushort* __restrict__ Wt,
                                              const int* __restrict__ cnt,
                                              ushort* __restrict__ Xh, int M) {
  __shared__ ushort WtT[16384];   // 128 cols x 128 k, swizzled, 32 KB
  const int tid  = threadIdx.x;
  const int lane = tid & 63;
  const int wv   = tid >> 6;      // wave 0..7
  const int cl   = lane & 15;
  const int g    = lane >> 4;
  const int rb = blockIdx.x * 128 + wv * 16;

  int rowc = rb + cl; if (rowc >= M) rowc = M - 1;
  const float* xr = X + (size_t)rowc * 128;
  ABu af[4];
  #pragma unroll
  for (int kk = 0; kk < 4; kk++) {
    float4v p = __builtin_nontemporal_load((const float4v*)&xr[kk * 32 + g * 8]);
    float4v q = __builtin_nontemporal_load((const float4v*)&xr[kk * 32 + g * 8 + 4]);
    af[kk].u[0] = pack_bf2(p.x, p.y);
    af[kk].u[1] = pack_bf2(p.z, p.w);
    af[kk].u[2] = pack_bf2(q.x, q.y);
    af[kk].u[3] = pack_bf2(q.z, q.w);
  }

  float dvr[4];
  #pragma unroll
  for (int r = 0; r < 4; r++) {
    int rw = rb + g * 4 + r; if (rw >= M) rw = M - 1;
    dvr[r] = rsqrtf((float)(cnt[rw] + 1));
  }

  #pragma unroll
  for (int it = 0; it < 4; it++) {
    int id = tid + it * 512;
    int c = id >> 4, j = id & 15;
    int4v chunk = *(const int4v*)((const char*)Wt + id * 16);
    int gr = (j ^ ((c & 15) >> 1)) & 15;
    *(int4v*)((char*)WtT + c * 256 + gr * 16) = chunk;
  }
  __syncthreads();

  #pragma unroll
  for (int ct = 0; ct < 8; ct++) {
    const char* wrow = (const char*)WtT + (ct * 16 + cl) * 256;
    f32x4 acc = {0.f, 0.f, 0.f, 0.f};
    #pragma unroll
    for (int kk = 0; kk < 4; kk++) {
      int grn = ((4 * kk + g) ^ (cl >> 1)) & 15;
      short8 bfrag = *(const short8*)(wrow + (grn << 4));
      acc = __builtin_amdgcn_mfma_f32_16x16x32_bf16(af[kk].v, bfrag, acc, 0, 0, 0);
    }
    #pragma unroll
    for (int r = 0; r < 4; r++) {
      int rw = rb + g * 4 + r;
      if (rw < M) Xh[(size_t)rw * 128 + ct * 16 + cl] = bf16_1(dvr[r] * acc[r]);
    }
  }
}

// One wave per node; tail-free unroll-8 gather over pre-scaled bf16 rows.
__global__ __launch_bounds__(256) void k_agg1(const uint32* __restrict__ Xh,
                                              const int* __restrict__ csr,
                                              const int* __restrict__ cnt,
                                              const float* __restrict__ b1,
                                              const float* __restrict__ wv,
                                              float* __restrict__ dz, int N) {
  int wid = (blockIdx.x * 256 + threadIdx.x) >> 6;
  int lane = threadIdx.x & 63;
  if (wid >= N) return;
  const int i = wid;
  int cv = cnt[i];
  int deg = cv; if (deg > CAP) deg = CAP;
  const int deg8 = (deg + 7) & ~7;
  const float di = rsqrtf((float)(cv + 1));
  int edge_reg = i;
  if (lane < deg8) edge_reg = __builtin_nontemporal_load(&csr[(size_t)i * CAP + lane]);

  uint32 vs = Xh[(size_t)i * 64 + lane];          // self-loop row
  float a0x = 0.f, a0y = 0.f, a1x = 0.f, a1y = 0.f;
  float a2x = 0.f, a2y = 0.f, a3x = 0.f, a3y = 0.f;
  float a4x = 0.f, a4y = 0.f, a5x = 0.f, a5y = 0.f;
  float a6x = 0.f, a6y = 0.f, a7x = 0.f, a7y = 0.f;

  for (int e = 0; e < deg8; e += 8) {
    int s0 = __builtin_amdgcn_readlane(edge_reg, e + 0);
    int s1 = __builtin_amdgcn_readlane(edge_reg, e + 1);
    int s2 = __builtin_amdgcn_readlane(edge_reg, e + 2);
    int s3 = __builtin_amdgcn_readlane(edge_reg, e + 3);
    int s4 = __builtin_amdgcn_readlane(edge_reg, e + 4);
    int s5 = __builtin_amdgcn_readlane(edge_reg, e + 5);
    int s6 = __builtin_amdgcn_readlane(edge_reg, e + 6);
    int s7 = __builtin_amdgcn_readlane(edge_reg, e + 7);
    uint32 v0 = Xh[(size_t)s0 * 64 + lane];
    uint32 v1 = Xh[(size_t)s1 * 64 + lane];
    uint32 v2 = Xh[(size_t)s2 * 64 + lane];
    uint32 v3 = Xh[(size_t)s3 * 64 + lane];
    uint32 v4 = Xh[(size_t)s4 * 64 + lane];
    uint32 v5 = Xh[(size_t)s5 * 64 + lane];
    uint32 v6 = Xh[(size_t)s6 * 64 + lane];
    uint32 v7 = Xh[(size_t)s7 * 64 + lane];
    a0x += bf_lo(v0); a0y += bf_hi(v0);
    a1x += bf_lo(v1); a1y += bf_hi(v1);
    a2x += bf_lo(v2); a2y += bf_hi(v2);
    a3x += bf_lo(v3); a3y += bf_hi(v3);
    a4x += bf_lo(v4); a4y += bf_hi(v4);
    a5x += bf_lo(v5); a5y += bf_hi(v5);
    a6x += bf_lo(v6); a6y += bf_hi(v6);
    a7x += bf_lo(v7); a7y += bf_hi(v7);
  }
  const float selfc = 1.0f - (float)(deg8 - deg);
  float sx = ((a0x + a1x) + (a2x + a3x)) + ((a4x + a5x) + (a6x + a7x));
  float sy = ((a0y + a1y) + (a2y + a3y)) + ((a4y + a5y) + (a6y + a7y));
  sx = fmaf(selfc, bf_lo(vs), sx);
  sy = fmaf(selfc, bf_hi(vs), sy);

  float2 bb = *(const float2*)&b1[lane * 2];
  float h0 = fmaxf(fmaf(di, sx, bb.x), 0.f);
  float h1 = fmaxf(fmaf(di, sy, bb.y), 0.f);
  float2 ww = *(const float2*)&wv[lane * 2];
  float part = fmaf(h0, ww.x, h1 * ww.y);
  #pragma unroll
  for (int m = 32; m > 0; m >>= 1) part += __shfl_xor(part, m, 64);
  if (lane == 0) dz[i] = di * part;
}

// out[i] = c0 + dinv[i] * (dz[i] + sum_in dz[src]); int4 csr loads over the
// self-padded deg8 range, padding corrected via (1 - npad) * dz[i].
__global__ __launch_bounds__(256) void k_out(const float* __restrict__ dz,
                                             const int* __restrict__ csr,
                                             const int* __restrict__ cnt,
                                             const float* __restrict__ c0,
                                             float* __restrict__ out, int N) {
  int i = blockIdx.x * 256 + threadIdx.x;
  if (i >= N) return;
  int cv = cnt[i];
  int deg = cv; if (deg > CAP) deg = CAP;
  const int deg8 = (deg + 7) & ~7;
  const int4v* __restrict__ edges = (const int4v*)(csr + (size_t)i * CAP);
  float s0 = (1.0f - (float)(deg8 - deg)) * dz[i];
  float s1 = 0.f, s2 = 0.f, s3 = 0.f;
  for (int e4 = 0; e4 < (deg8 >> 2); e4 += 2) {
    int4v q0 = __builtin_nontemporal_load(&edges[e4]);
    int4v q1 = __builtin_nontemporal_load(&edges[e4 + 1]);
    s0 += dz[q0.x]; s1 += dz[q0.y]; s2 += dz[q0.z]; s3 += dz[q0.w];
    s0 += dz[q1.x]; s1 += dz[q1.y]; s2 += dz[q1.z]; s3 += dz[q1.w];
  }
  out[i] = rsqrtf((float)(cv + 1)) * ((s0 + s1) + (s2 + s3)) + c0[0];
}

extern "C" void kernel_launch(void* const* d_in, const int* in_sizes, int n_in,
                              void* d_out, int out_size, void* d_ws, size_t ws_size,
                              hipStream_t stream) {
  const float* x   = (const float*)d_in[0];
  const int*   ei  = (const int*)d_in[1];   // int inputs arrive as int32
  // d_in[2] edge_weight: unused by reference
  const float* W1  = (const float*)d_in[3];
  const float* b1  = (const float*)d_in[4];
  const float* W2  = (const float*)d_in[5];
  const float* b2  = (const float*)d_in[6];
  const float* Wfc = (const float*)d_in[7];
  const float* bfc = (const float*)d_in[8];
  float* out = (float*)d_out;

  const int N = in_sizes[0] / 128;   // 100000
  const int E = in_sizes[1] / 2;     // 1600000
  const int NB = (N + 255) >> 8;     // 391 buckets

  // workspace layout (~65 MB)
  char* ws = (char*)d_ws;
  ushort* Xh = (ushort*)(ws);                               // N*128 bf16, 25.6MB
  size_t off = (size_t)N * 256;
  int* csr   = (int*)(ws + off); off += (size_t)N * 256;    // 25.6MB
  int* stage = (int*)(ws + off); off += (size_t)8 * NB * GSLOT * 4;  // 12.81MB
  int* cnt   = (int*)(ws + off); off += (size_t)N * 4;
  float* dz  = (float*)(ws + off); off += (size_t)N * 4;
  int* bcnt  = (int*)(ws + off); off += (size_t)8 * NB * 4;
  ushort* Wt = (ushort*)(ws + off); off += 16384 * 2;       // 32KB bf16 W1^T
  float* wv  = (float*)(ws + off); off += 512;
  float* c0  = (float*)(ws + off);

  hipMemsetAsync(bcnt, 0, (size_t)8 * NB * 4, stream);
  hipLaunchKernelGGL(k_part1, dim3((E + CHUNK - 1) / CHUNK), dim3(512), 0, stream,
                     ei, bcnt, stage, E, N, NB);
  hipLaunchKernelGGL(k_fill2, dim3(NB + 1), dim3(512), 0, stream,
                     stage, bcnt, csr, cnt, N, NB, W1, Wt, W2, Wfc, b2, bfc, wv, c0);
  hipLaunchKernelGGL(k_gemm,  dim3((N + 127) / 128), dim3(512), 0, stream,
                     x, Wt, cnt, Xh, N);
  hipLaunchKernelGGL(k_agg1, dim3(((size_t)N * 64 + 255) / 256), dim3(256), 0, stream,
                     (const uint32*)Xh, csr, cnt, b1, wv, dz, N);
  hipLaunchKernelGGL(k_out,  dim3((N + 255) / 256), dim3(256), 0, stream,
                     dz, csr, cnt, c0, out, N);
}